// Round 1
// baseline (2543.541 us; speedup 1.0000x reference)
//
#include <hip/hip_runtime.h>
#include <math.h>

// Problem constants (fixed by reference: b=4, n=2048, d=1024, H=16, DH=64)
#define BB    4
#define NN    2048
#define DD    1024
#define HH    16
#define DHD   64
#define INNER 1024
#define SCALE 0.125f
// log2(10000)/16 for inv_freq = 2^(-fi * LOG2_10K_D16)
#define LOG2_10K_D16 0.8304820237218406f

// ---------- bf16 helpers (manual RNE to be deterministic) ----------
static __device__ __forceinline__ unsigned short f2bf(float f) {
    union { float f; unsigned int u; } v; v.f = f;
    unsigned int u = v.u;
    u += 0x7fffu + ((u >> 16) & 1u);
    return (unsigned short)(u >> 16);
}
static __device__ __forceinline__ float bf2f(unsigned short h) {
    union { unsigned int u; float f; } v; v.u = ((unsigned int)h) << 16;
    return v.f;
}

// =====================================================================
// Kernel 1: fused QKV projection + RoPE + head-split transpose.
// Treats output as one 8192 x 3072 GEMM: cols [0,1024)=Q, [1024,2048)=K,
// [2048,3072)=V.  64x64 tile per block, 256 threads, 4x4 microtile.
// Epilogue applies RoPE (pairs land inside each thread's 4 cols) and
// writes bf16 q/k/v in [b][h][n][dh] layout.
// =====================================================================
__global__ __launch_bounds__(256) void proj_qkv_kernel(
    const float* __restrict__ X, const float* __restrict__ Wq,
    const float* __restrict__ Wkv,
    unsigned short* __restrict__ qb, unsigned short* __restrict__ kb,
    unsigned short* __restrict__ vb)
{
    __shared__ __align__(16) float As[16][68];  // [k][m], pad -> 2-way max
    __shared__ __align__(16) float Bs[16][68];  // [k][n], 68*4B rows stay 16B-aligned

    const int t  = threadIdx.x;
    const int m0 = blockIdx.y * 64;   // row tile   (0..8191)
    const int n0 = blockIdx.x * 64;   // col tile   (0..3071)

    const float* Wp; int ldb, bn0;
    if (n0 < 1024) { Wp = Wq;  ldb = 1024; bn0 = n0;        }
    else           { Wp = Wkv; ldb = 2048; bn0 = n0 - 1024; }

    const int a_row = t >> 2,  a_c4 = (t & 3) * 4;     // A: 64 rows x 16 k
    const int b_row = t >> 4,  b_c4 = (t & 15) * 4;    // B: 16 k  x 64 cols
    const int tm = (t >> 4) * 4, tn = (t & 15) * 4;

    float acc[4][4] = {};

    for (int k0 = 0; k0 < DD; k0 += 16) {
        const float4 av = *(const float4*)(X  + (size_t)(m0 + a_row) * DD  + k0 + a_c4);
        const float4 bv = *(const float4*)(Wp + (size_t)(k0 + b_row) * ldb + bn0 + b_c4);
        __syncthreads();   // previous tile's compute done before overwrite
        As[a_c4 + 0][a_row] = av.x;
        As[a_c4 + 1][a_row] = av.y;
        As[a_c4 + 2][a_row] = av.z;
        As[a_c4 + 3][a_row] = av.w;
        *(float4*)(&Bs[b_row][b_c4]) = bv;
        __syncthreads();
        #pragma unroll
        for (int kk = 0; kk < 16; ++kk) {
            float a[4], b[4];
            #pragma unroll
            for (int i = 0; i < 4; ++i) a[i] = As[kk][tm + i];
            #pragma unroll
            for (int j = 0; j < 4; ++j) b[j] = Bs[kk][tn + j];
            #pragma unroll
            for (int i = 0; i < 4; ++i)
                #pragma unroll
                for (int j = 0; j < 4; ++j)
                    acc[i][j] = fmaf(a[i], b[j], acc[i][j]);
        }
    }

    // ---------------- epilogue: RoPE + scatter ----------------
    const int sec = n0 >> 10;              // 0=q 1=k 2=v
    const int cc  = (n0 & 1023) + tn;      // col within section
    const int h   = cc >> 6;
    const int dh0 = cc & 63;               // multiple of 4
    const bool do_rope = (sec < 2) && (dh0 < 32);
    // pair frequency indices for cols (dh0,dh0+1) and (dh0+2,dh0+3)
    const float if0 = exp2f(-(float)(dh0 >> 1)       * LOG2_10K_D16);
    const float if1 = exp2f(-(float)((dh0 >> 1) + 1) * LOG2_10K_D16);

    unsigned short* dst = (sec == 0) ? qb : ((sec == 1) ? kb : vb);

    #pragma unroll
    for (int i = 0; i < 4; ++i) {
        const int r_g = m0 + tm + i;
        const int b   = r_g >> 11;         // /2048
        const int n   = r_g & 2047;
        float o0 = acc[i][0], o1 = acc[i][1], o2 = acc[i][2], o3 = acc[i][3];
        if (do_rope) {
            const float fn = (float)n;
            const float a0 = fn * if0, a1 = fn * if1;
            const float c0 = cosf(a0), s0 = sinf(a0);
            const float c1 = cosf(a1), s1 = sinf(a1);
            const float y0 = o0 * c0 - o1 * s0;
            const float y1 = o1 * c0 + o0 * s0;
            const float y2 = o2 * c1 - o3 * s1;
            const float y3 = o3 * c1 + o2 * s1;
            o0 = y0; o1 = y1; o2 = y2; o3 = y3;
        }
        unsigned short* p = dst + (((size_t)b * HH + h) * NN + n) * DHD + dh0;
        p[0] = f2bf(o0); p[1] = f2bf(o1); p[2] = f2bf(o2); p[3] = f2bf(o3);
    }
}

// =====================================================================
// Kernel 2: flash-style attention, fp32 math on bf16 q/k/v.
// grid = (N/64, B*H).  Per block: 64 queries x full 2048 keys in 64-key
// tiles with online softmax.  256 threads, 4x4 microtiles for both
// S = q k^T and O += P v.  k and v share one LDS buffer (loaded in
// sequence) to stay under 64 KiB static LDS.
// =====================================================================
__global__ __launch_bounds__(256) void attn_kernel(
    const unsigned short* __restrict__ qb, const unsigned short* __restrict__ kb,
    const unsigned short* __restrict__ vb, float* __restrict__ ao)
{
    __shared__ float qs [64][65];
    __shared__ float kvs[64][65];   // holds k-tile during S, v-tile during PV
    __shared__ float ps [64][65];   // scores -> probabilities
    __shared__ float m_s[64], l_s[64], al_s[64];
    __shared__ float red [64][4];
    __shared__ float red2[64][4];

    const int t  = threadIdx.x;
    const int q0 = blockIdx.x * 64;
    const int bh = blockIdx.y;
    const size_t hb = (size_t)bh * NN * DHD;

    const int lrow = t >> 2, lseg = (t & 3) * 16;   // cooperative tile loads
    const int tm = (t >> 4) * 4, tn = (t & 15) * 4; // 4x4 microtile coords
    const int rr = t >> 2, qq = t & 3, kkb = qq * 16; // softmax row split

    { // load q tile (64 x 64)
        const unsigned short* src = qb + hb + (size_t)(q0 + lrow) * DHD + lseg;
        #pragma unroll
        for (int j = 0; j < 16; ++j) qs[lrow][lseg + j] = bf2f(src[j]);
    }
    if (t < 64) { m_s[t] = -1e30f; l_s[t] = 0.0f; }

    float acc[4][4] = {};

    for (int kt = 0; kt < NN / 64; ++kt) {
        __syncthreads();  // prior PV (reader of kvs) done
        { // load k tile
            const unsigned short* src = kb + hb + (size_t)(kt * 64 + lrow) * DHD + lseg;
            #pragma unroll
            for (int j = 0; j < 16; ++j) kvs[lrow][lseg + j] = bf2f(src[j]);
        }
        __syncthreads();

        // ---- S = scale * q k^T ----
        float sacc[4][4] = {};
        #pragma unroll 8
        for (int d = 0; d < 64; ++d) {
            float a[4], b[4];
            #pragma unroll
            for (int i = 0; i < 4; ++i) a[i] = qs[tm + i][d];
            #pragma unroll
            for (int j = 0; j < 4; ++j) b[j] = kvs[tn + j][d];
            #pragma unroll
            for (int i = 0; i < 4; ++i)
                #pragma unroll
                for (int j = 0; j < 4; ++j)
                    sacc[i][j] = fmaf(a[i], b[j], sacc[i][j]);
        }
        #pragma unroll
        for (int i = 0; i < 4; ++i)
            #pragma unroll
            for (int j = 0; j < 4; ++j)
                ps[tm + i][tn + j] = sacc[i][j] * SCALE;
        __syncthreads();

        // ---- online softmax: 4 threads per row, 16 cols each ----
        float lm = -1e30f;
        #pragma unroll
        for (int j = 0; j < 16; ++j) lm = fmaxf(lm, ps[rr][kkb + j]);
        red[rr][qq] = lm;
        const float mold = m_s[rr];   // read BEFORE the barrier; written after it
        __syncthreads();
        const float mloc = fmaxf(fmaxf(red[rr][0], red[rr][1]),
                                 fmaxf(red[rr][2], red[rr][3]));
        const float mnew = fmaxf(mold, mloc);
        float lsum = 0.0f;
        #pragma unroll
        for (int j = 0; j < 16; ++j) {
            const float p = expf(ps[rr][kkb + j] - mnew);
            ps[rr][kkb + j] = p;
            lsum += p;
        }
        red2[rr][qq] = lsum;
        if (qq == 0) { al_s[rr] = expf(mold - mnew); m_s[rr] = mnew; }
        __syncthreads();

        if (t < 64)
            l_s[t] = l_s[t] * al_s[t] + red2[t][0] + red2[t][1] + red2[t][2] + red2[t][3];
        { // load v tile into kvs (k no longer needed)
            const unsigned short* src = vb + hb + (size_t)(kt * 64 + lrow) * DHD + lseg;
            #pragma unroll
            for (int j = 0; j < 16; ++j) kvs[lrow][lseg + j] = bf2f(src[j]);
        }
        __syncthreads();

        // ---- O = O*alpha + P v ----
        float al[4];
        #pragma unroll
        for (int i = 0; i < 4; ++i) al[i] = al_s[tm + i];
        #pragma unroll
        for (int i = 0; i < 4; ++i)
            #pragma unroll
            for (int j = 0; j < 4; ++j) acc[i][j] *= al[i];
        #pragma unroll 8
        for (int kk = 0; kk < 64; ++kk) {
            float a[4], b[4];
            #pragma unroll
            for (int i = 0; i < 4; ++i) a[i] = ps[tm + i][kk];
            #pragma unroll
            for (int j = 0; j < 4; ++j) b[j] = kvs[kk][tn + j];
            #pragma unroll
            for (int i = 0; i < 4; ++i)
                #pragma unroll
                for (int j = 0; j < 4; ++j)
                    acc[i][j] = fmaf(a[i], b[j], acc[i][j]);
        }
    }

    __syncthreads();
    const int b = bh >> 4, h = bh & 15;
    #pragma unroll
    for (int i = 0; i < 4; ++i) {
        const float linv = 1.0f / l_s[tm + i];
        const int n = q0 + tm + i;
        float* dst = ao + ((size_t)b * NN + n) * INNER + h * DHD + tn;
        #pragma unroll
        for (int j = 0; j < 4; ++j) dst[j] = acc[i][j] * linv;
    }
}

// =====================================================================
// Kernel 3: output projection  out = ao @ Wout + bout   (8192x1024 fp32)
// =====================================================================
__global__ __launch_bounds__(256) void out_proj_kernel(
    const float* __restrict__ A, const float* __restrict__ W,
    const float* __restrict__ bias, float* __restrict__ C)
{
    __shared__ __align__(16) float As[16][68];
    __shared__ __align__(16) float Bs[16][68];

    const int t  = threadIdx.x;
    const int m0 = blockIdx.y * 64;
    const int n0 = blockIdx.x * 64;

    const int a_row = t >> 2,  a_c4 = (t & 3) * 4;
    const int b_row = t >> 4,  b_c4 = (t & 15) * 4;
    const int tm = (t >> 4) * 4, tn = (t & 15) * 4;

    float acc[4][4] = {};

    for (int k0 = 0; k0 < INNER; k0 += 16) {
        const float4 av = *(const float4*)(A + (size_t)(m0 + a_row) * INNER + k0 + a_c4);
        const float4 bv = *(const float4*)(W + (size_t)(k0 + b_row) * DD + n0 + b_c4);
        __syncthreads();
        As[a_c4 + 0][a_row] = av.x;
        As[a_c4 + 1][a_row] = av.y;
        As[a_c4 + 2][a_row] = av.z;
        As[a_c4 + 3][a_row] = av.w;
        *(float4*)(&Bs[b_row][b_c4]) = bv;
        __syncthreads();
        #pragma unroll
        for (int kk = 0; kk < 16; ++kk) {
            float a[4], b[4];
            #pragma unroll
            for (int i = 0; i < 4; ++i) a[i] = As[kk][tm + i];
            #pragma unroll
            for (int j = 0; j < 4; ++j) b[j] = Bs[kk][tn + j];
            #pragma unroll
            for (int i = 0; i < 4; ++i)
                #pragma unroll
                for (int j = 0; j < 4; ++j)
                    acc[i][j] = fmaf(a[i], b[j], acc[i][j]);
        }
    }

    #pragma unroll
    for (int i = 0; i < 4; ++i) {
        const int r = m0 + tm + i;
        float* dst = C + (size_t)r * DD + n0 + tn;
        #pragma unroll
        for (int j = 0; j < 4; ++j) dst[j] = acc[i][j] + bias[n0 + tn + j];
    }
}

// =====================================================================
extern "C" void kernel_launch(void* const* d_in, const int* in_sizes, int n_in,
                              void* d_out, int out_size, void* d_ws, size_t ws_size,
                              hipStream_t stream)
{
    const float* X    = (const float*)d_in[0];   // (4,2048,1024)
    const float* Wq   = (const float*)d_in[1];   // (1024,1024)
    const float* Wkv  = (const float*)d_in[2];   // (1024,2048)
    const float* Wout = (const float*)d_in[3];   // (1024,1024)
    const float* bout = (const float*)d_in[4];   // (1024,)
    float* out = (float*)d_out;

    // ws layout: qb,kb,vb bf16 [b][h][n][64] (16.78 MB each) + ao fp32 (33.55 MB)
    const size_t qkv_elems = (size_t)BB * HH * NN * DHD;   // 8388608
    unsigned short* qb = (unsigned short*)d_ws;
    unsigned short* kb = qb + qkv_elems;
    unsigned short* vb = kb + qkv_elems;
    float* ao = (float*)(vb + qkv_elems);

    // Stage 1: QKV projection + RoPE + head split   (8192 x 3072 GEMM)
    proj_qkv_kernel<<<dim3(3072 / 64, 8192 / 64), 256, 0, stream>>>(
        X, Wq, Wkv, qb, kb, vb);

    // Stage 2: attention (flash-style, online softmax)
    attn_kernel<<<dim3(NN / 64, BB * HH), 256, 0, stream>>>(qb, kb, vb, ao);

    // Stage 3: output projection + bias
    out_proj_kernel<<<dim3(DD / 64, 8192 / 64), 256, 0, stream>>>(
        ao, Wout, bout, out);
}

// Round 2
// 1218.654 us; speedup vs baseline: 2.0872x; 2.0872x over previous
//
#include <hip/hip_runtime.h>
#include <math.h>

// Problem constants (fixed by reference: b=4, n=2048, d=1024, H=16, DH=64)
#define BB    4
#define NN    2048
#define DD    1024
#define HH    16
#define DHD   64
#define INNER 1024
#define SCALE 0.125f
// log2(10000)/16 for inv_freq = 2^(-fi * LOG2_10K_D16)
#define LOG2_10K_D16 0.8304820237218406f
// SCALE * log2(e): scores kept in log2-domain so softmax uses exp2 (native v_exp_f32)
#define SCALE_LOG2E 0.1803368801111601f

typedef short bf16x8 __attribute__((ext_vector_type(8)));   // 8 bf16 = 4 VGPRs
typedef float f32x4  __attribute__((ext_vector_type(4)));

// ---------- bf16 helpers (manual RNE to be deterministic) ----------
static __device__ __forceinline__ unsigned short f2bf(float f) {
    union { float f; unsigned int u; } v; v.f = f;
    unsigned int u = v.u;
    u += 0x7fffu + ((u >> 16) & 1u);
    return (unsigned short)(u >> 16);
}
static __device__ __forceinline__ float bf2f(unsigned short h) {
    union { unsigned int u; float f; } v; v.u = ((unsigned int)h) << 16;
    return v.f;
}

// =====================================================================
// Kernel 1: fused QKV projection + RoPE + head-split transpose (fp32).
// (unchanged from R1 — converting to MFMA is next round's change)
// =====================================================================
__global__ __launch_bounds__(256) void proj_qkv_kernel(
    const float* __restrict__ X, const float* __restrict__ Wq,
    const float* __restrict__ Wkv,
    unsigned short* __restrict__ qb, unsigned short* __restrict__ kb,
    unsigned short* __restrict__ vb)
{
    __shared__ __align__(16) float As[16][68];
    __shared__ __align__(16) float Bs[16][68];

    const int t  = threadIdx.x;
    const int m0 = blockIdx.y * 64;
    const int n0 = blockIdx.x * 64;

    const float* Wp; int ldb, bn0;
    if (n0 < 1024) { Wp = Wq;  ldb = 1024; bn0 = n0;        }
    else           { Wp = Wkv; ldb = 2048; bn0 = n0 - 1024; }

    const int a_row = t >> 2,  a_c4 = (t & 3) * 4;
    const int b_row = t >> 4,  b_c4 = (t & 15) * 4;
    const int tm = (t >> 4) * 4, tn = (t & 15) * 4;

    float acc[4][4] = {};

    for (int k0 = 0; k0 < DD; k0 += 16) {
        const float4 av = *(const float4*)(X  + (size_t)(m0 + a_row) * DD  + k0 + a_c4);
        const float4 bv = *(const float4*)(Wp + (size_t)(k0 + b_row) * ldb + bn0 + b_c4);
        __syncthreads();
        As[a_c4 + 0][a_row] = av.x;
        As[a_c4 + 1][a_row] = av.y;
        As[a_c4 + 2][a_row] = av.z;
        As[a_c4 + 3][a_row] = av.w;
        *(float4*)(&Bs[b_row][b_c4]) = bv;
        __syncthreads();
        #pragma unroll
        for (int kk = 0; kk < 16; ++kk) {
            float a[4], b[4];
            #pragma unroll
            for (int i = 0; i < 4; ++i) a[i] = As[kk][tm + i];
            #pragma unroll
            for (int j = 0; j < 4; ++j) b[j] = Bs[kk][tn + j];
            #pragma unroll
            for (int i = 0; i < 4; ++i)
                #pragma unroll
                for (int j = 0; j < 4; ++j)
                    acc[i][j] = fmaf(a[i], b[j], acc[i][j]);
        }
    }

    const int sec = n0 >> 10;
    const int cc  = (n0 & 1023) + tn;
    const int h   = cc >> 6;
    const int dh0 = cc & 63;
    const bool do_rope = (sec < 2) && (dh0 < 32);
    const float if0 = exp2f(-(float)(dh0 >> 1)       * LOG2_10K_D16);
    const float if1 = exp2f(-(float)((dh0 >> 1) + 1) * LOG2_10K_D16);

    unsigned short* dst = (sec == 0) ? qb : ((sec == 1) ? kb : vb);

    #pragma unroll
    for (int i = 0; i < 4; ++i) {
        const int r_g = m0 + tm + i;
        const int b   = r_g >> 11;
        const int n   = r_g & 2047;
        float o0 = acc[i][0], o1 = acc[i][1], o2 = acc[i][2], o3 = acc[i][3];
        if (do_rope) {
            const float fn = (float)n;
            const float a0 = fn * if0, a1 = fn * if1;
            const float c0 = cosf(a0), s0 = sinf(a0);
            const float c1 = cosf(a1), s1 = sinf(a1);
            const float y0 = o0 * c0 - o1 * s0;
            const float y1 = o1 * c0 + o0 * s0;
            const float y2 = o2 * c1 - o3 * s1;
            const float y3 = o3 * c1 + o2 * s1;
            o0 = y0; o1 = y1; o2 = y2; o3 = y3;
        }
        unsigned short* p = dst + (((size_t)b * HH + h) * NN + n) * DHD + dh0;
        p[0] = f2bf(o0); p[1] = f2bf(o1); p[2] = f2bf(o2); p[3] = f2bf(o3);
    }
}

// =====================================================================
// Kernel 2: flash attention with bf16 MFMA (16x16x32).
// grid = (N/64, B*H), 256 threads = 4 waves; wave w owns 16 queries.
// K-tile = 64 keys: S = Q K^T via MFMA (K staged [key][dh]), online
// softmax in registers (xor-shuffle row reduce), P -> LDS (bf16, per
// wave) to convert C-layout -> A-layout, O += P V via MFMA (V staged
// transposed [dh][key]).
// MFMA layouts (m89/m120-verified):
//   A: A[m=lane&15][k=quad*8+j]   B: B[n=lane&15][k=quad*8+j]
//   C/D: col=lane&15, row=quad*4+reg
// =====================================================================
__global__ __launch_bounds__(256) void attn_kernel(
    const unsigned short* __restrict__ qb, const unsigned short* __restrict__ kb,
    const unsigned short* __restrict__ vb, float* __restrict__ ao)
{
    // rows padded 64 -> 72 elems (144 B): b128 frag reads land 2-way max (free)
    __shared__ __align__(16) unsigned short ks[64][72];   // [key][dh]
    __shared__ __align__(16) unsigned short vt[64][72];   // [dh][key]
    __shared__ __align__(16) unsigned short ps[4][16][72]; // per-wave P [q][key]

    const int t     = threadIdx.x;
    const int w     = t >> 6;          // wave 0..3
    const int lane  = t & 63;
    const int lane4 = lane & 15;
    const int quad  = lane >> 4;
    const int quad8 = quad * 8;

    const int q0 = blockIdx.x * 64;
    const int bh = blockIdx.y;
    const size_t hb = (size_t)bh * NN * DHD;

    // ---- Q A-fragments (held in registers for the whole kernel) ----
    const unsigned short* qrow = qb + hb + (size_t)(q0 + w * 16 + lane4) * DHD;
    const bf16x8 qf0 = *(const bf16x8*)(qrow + quad8);        // dh 0..31
    const bf16x8 qf1 = *(const bf16x8*)(qrow + 32 + quad8);   // dh 32..63

    // staging index maps
    const int st_key = t >> 3;            // 0..31 (K staging, +32 second pass)
    const int st_dh  = (t & 7) * 8;

    float m_r[4], l_r[4];
    f32x4 o[4];
    #pragma unroll
    for (int r = 0; r < 4; ++r) { m_r[r] = -1e30f; l_r[r] = 0.0f; }
    #pragma unroll
    for (int c = 0; c < 4; ++c) o[c] = (f32x4){0.f, 0.f, 0.f, 0.f};

    for (int kt = 0; kt < NN / 64; ++kt) {
        __syncthreads();   // prior iteration's MFMA reads of ks/vt complete

        // ---- stage K tile [key][dh], fully coalesced, b128 writes ----
        #pragma unroll
        for (int p = 0; p < 2; ++p) {
            const int key = st_key + p * 32;
            const bf16x8 val = *(const bf16x8*)(kb + hb + (size_t)(kt * 64 + key) * DHD + st_dh);
            *(bf16x8*)&ks[key][st_dh] = val;
        }
        // ---- stage V tile transposed [dh][key]; wave w covers dh w*16..+16 ----
        #pragma unroll
        for (int p = 0; p < 2; ++p) {
            const int dh0 = w * 16 + p * 8;
            const bf16x8 val = *(const bf16x8*)(vb + hb + (size_t)(kt * 64 + lane) * DHD + dh0);
            #pragma unroll
            for (int j = 0; j < 8; ++j) vt[dh0 + j][lane] = (unsigned short)val[j];
        }
        __syncthreads();

        // ---- S = Q K^T  (4 col-tiles x 2 K-halves) ----
        f32x4 sc[4];
        #pragma unroll
        for (int c = 0; c < 4; ++c) {
            const bf16x8 b0 = *(const bf16x8*)&ks[c * 16 + lane4][quad8];
            const bf16x8 b1 = *(const bf16x8*)&ks[c * 16 + lane4][32 + quad8];
            f32x4 z = (f32x4){0.f, 0.f, 0.f, 0.f};
            z = __builtin_amdgcn_mfma_f32_16x16x32_bf16(qf0, b0, z, 0, 0, 0);
            z = __builtin_amdgcn_mfma_f32_16x16x32_bf16(qf1, b1, z, 0, 0, 0);
            sc[c] = z;
        }

        // ---- online softmax (log2 domain) ----
        float tv[4][4];   // [ctile][row-reg]
        #pragma unroll
        for (int c = 0; c < 4; ++c)
            #pragma unroll
            for (int r = 0; r < 4; ++r)
                tv[c][r] = sc[c][r] * SCALE_LOG2E;

        float mrow[4];
        #pragma unroll
        for (int r = 0; r < 4; ++r)
            mrow[r] = fmaxf(fmaxf(tv[0][r], tv[1][r]), fmaxf(tv[2][r], tv[3][r]));
        #pragma unroll
        for (int off = 1; off <= 8; off <<= 1)
            #pragma unroll
            for (int r = 0; r < 4; ++r)
                mrow[r] = fmaxf(mrow[r], __shfl_xor(mrow[r], off));

        float alpha[4], rsum[4];
        #pragma unroll
        for (int r = 0; r < 4; ++r) {
            const float mnew = fmaxf(m_r[r], mrow[r]);
            alpha[r] = exp2f(m_r[r] - mnew);
            m_r[r] = mnew;
            rsum[r] = 0.0f;
        }
        #pragma unroll
        for (int c = 0; c < 4; ++c)
            #pragma unroll
            for (int r = 0; r < 4; ++r) {
                const float p = exp2f(tv[c][r] - m_r[r]);
                const unsigned short pb = f2bf(p);
                ps[w][quad * 4 + r][c * 16 + lane4] = pb;
                rsum[r] += bf2f(pb);   // sum the ROUNDED p: consistent with PV
            }
        #pragma unroll
        for (int off = 1; off <= 8; off <<= 1)
            #pragma unroll
            for (int r = 0; r < 4; ++r)
                rsum[r] += __shfl_xor(rsum[r], off);
        #pragma unroll
        for (int r = 0; r < 4; ++r)
            l_r[r] = l_r[r] * alpha[r] + rsum[r];

        // rescale O
        #pragma unroll
        for (int c = 0; c < 4; ++c)
            #pragma unroll
            for (int r = 0; r < 4; ++r)
                o[c][r] *= alpha[r];

        // ---- P: C-layout -> A-layout via per-wave LDS (wave-local, no barrier) ----
        const bf16x8 pf0 = *(const bf16x8*)&ps[w][lane4][quad8];        // keys 0..31
        const bf16x8 pf1 = *(const bf16x8*)&ps[w][lane4][32 + quad8];   // keys 32..63

        // ---- O += P V   (4 dh-tiles x 2 key-halves) ----
        #pragma unroll
        for (int c = 0; c < 4; ++c) {
            const bf16x8 v0 = *(const bf16x8*)&vt[c * 16 + lane4][quad8];
            const bf16x8 v1 = *(const bf16x8*)&vt[c * 16 + lane4][32 + quad8];
            o[c] = __builtin_amdgcn_mfma_f32_16x16x32_bf16(pf0, v0, o[c], 0, 0, 0);
            o[c] = __builtin_amdgcn_mfma_f32_16x16x32_bf16(pf1, v1, o[c], 0, 0, 0);
        }
    }

    // ---- epilogue: normalize, write ao[b][n][h*64+dh] ----
    const int b = bh >> 4, h = bh & 15;
    float linv[4];
    #pragma unroll
    for (int r = 0; r < 4; ++r) linv[r] = 1.0f / l_r[r];
    #pragma unroll
    for (int c = 0; c < 4; ++c)
        #pragma unroll
        for (int r = 0; r < 4; ++r) {
            const int n = q0 + w * 16 + quad * 4 + r;
            ao[((size_t)b * NN + n) * INNER + h * DHD + c * 16 + lane4] = o[c][r] * linv[r];
        }
}

// =====================================================================
// Kernel 3: output projection  out = ao @ Wout + bout   (8192x1024 fp32)
// =====================================================================
__global__ __launch_bounds__(256) void out_proj_kernel(
    const float* __restrict__ A, const float* __restrict__ W,
    const float* __restrict__ bias, float* __restrict__ C)
{
    __shared__ __align__(16) float As[16][68];
    __shared__ __align__(16) float Bs[16][68];

    const int t  = threadIdx.x;
    const int m0 = blockIdx.y * 64;
    const int n0 = blockIdx.x * 64;

    const int a_row = t >> 2,  a_c4 = (t & 3) * 4;
    const int b_row = t >> 4,  b_c4 = (t & 15) * 4;
    const int tm = (t >> 4) * 4, tn = (t & 15) * 4;

    float acc[4][4] = {};

    for (int k0 = 0; k0 < INNER; k0 += 16) {
        const float4 av = *(const float4*)(A + (size_t)(m0 + a_row) * INNER + k0 + a_c4);
        const float4 bv = *(const float4*)(W + (size_t)(k0 + b_row) * DD + n0 + b_c4);
        __syncthreads();
        As[a_c4 + 0][a_row] = av.x;
        As[a_c4 + 1][a_row] = av.y;
        As[a_c4 + 2][a_row] = av.z;
        As[a_c4 + 3][a_row] = av.w;
        *(float4*)(&Bs[b_row][b_c4]) = bv;
        __syncthreads();
        #pragma unroll
        for (int kk = 0; kk < 16; ++kk) {
            float a[4], b[4];
            #pragma unroll
            for (int i = 0; i < 4; ++i) a[i] = As[kk][tm + i];
            #pragma unroll
            for (int j = 0; j < 4; ++j) b[j] = Bs[kk][tn + j];
            #pragma unroll
            for (int i = 0; i < 4; ++i)
                #pragma unroll
                for (int j = 0; j < 4; ++j)
                    acc[i][j] = fmaf(a[i], b[j], acc[i][j]);
        }
    }

    #pragma unroll
    for (int i = 0; i < 4; ++i) {
        const int r = m0 + tm + i;
        float* dst = C + (size_t)r * DD + n0 + tn;
        #pragma unroll
        for (int j = 0; j < 4; ++j) dst[j] = acc[i][j] + bias[n0 + tn + j];
    }
}

// =====================================================================
extern "C" void kernel_launch(void* const* d_in, const int* in_sizes, int n_in,
                              void* d_out, int out_size, void* d_ws, size_t ws_size,
                              hipStream_t stream)
{
    const float* X    = (const float*)d_in[0];   // (4,2048,1024)
    const float* Wq   = (const float*)d_in[1];   // (1024,1024)
    const float* Wkv  = (const float*)d_in[2];   // (1024,2048)
    const float* Wout = (const float*)d_in[3];   // (1024,1024)
    const float* bout = (const float*)d_in[4];   // (1024,)
    float* out = (float*)d_out;

    const size_t qkv_elems = (size_t)BB * HH * NN * DHD;   // 8388608
    unsigned short* qb = (unsigned short*)d_ws;
    unsigned short* kb = qb + qkv_elems;
    unsigned short* vb = kb + qkv_elems;
    float* ao = (float*)(vb + qkv_elems);

    proj_qkv_kernel<<<dim3(3072 / 64, 8192 / 64), 256, 0, stream>>>(
        X, Wq, Wkv, qb, kb, vb);

    attn_kernel<<<dim3(NN / 64, BB * HH), 256, 0, stream>>>(qb, kb, vb, ao);

    out_proj_kernel<<<dim3(DD / 64, 8192 / 64), 256, 0, stream>>>(
        ao, Wout, bout, out);
}

// Round 3
// 462.586 us; speedup vs baseline: 5.4985x; 2.6344x over previous
//
#include <hip/hip_runtime.h>
#include <math.h>

// Problem constants (fixed by reference: b=4, n=2048, d=1024, H=16, DH=64)
#define BB    4
#define NN    2048
#define DD    1024
#define HH    16
#define DHD   64
#define INNER 1024
// log2(10000)/16 for inv_freq = 2^(-f * LOG2_10K_D16)
#define LOG2_10K_D16 0.8304820237218406f
// SCALE * log2(e): attention scores in log2-domain -> native v_exp_f32
#define SCALE_LOG2E 0.1803368801111601f

typedef short bf16x8 __attribute__((ext_vector_type(8)));   // 8 bf16 = 4 VGPRs
typedef float f32x4  __attribute__((ext_vector_type(4)));
typedef unsigned short u16x8 __attribute__((ext_vector_type(8)));

// async 16B/lane global->LDS (lane i lands at wave-uniform base + i*16)
#define ASYNC16(g, l) __builtin_amdgcn_global_load_lds( \
    (const __attribute__((address_space(1))) void*)(g),  \
    (__attribute__((address_space(3))) void*)(l), 16, 0, 0)

// ---------- bf16 helpers (manual RNE to be deterministic) ----------
static __device__ __forceinline__ unsigned short f2bf(float f) {
    union { float f; unsigned int u; } v; v.f = f;
    unsigned int u = v.u;
    u += 0x7fffu + ((u >> 16) & 1u);
    return (unsigned short)(u >> 16);
}
static __device__ __forceinline__ float bf2f(unsigned short h) {
    union { unsigned int u; float f; } v; v.u = ((unsigned int)h) << 16;
    return v.f;
}

// =====================================================================
// Pre-pass A: cast X fp32 -> bf16 (copy-cast, 8 elems/thread)
// =====================================================================
__global__ __launch_bounds__(256) void cast_x_kernel(
    const float* __restrict__ X, unsigned short* __restrict__ Xb)
{
    const size_t i = ((size_t)blockIdx.x * 256 + threadIdx.x) * 8;
    const float4 a = *(const float4*)(X + i);
    const float4 b = *(const float4*)(X + i + 4);
    u16x8 o;
    o[0] = f2bf(a.x); o[1] = f2bf(a.y); o[2] = f2bf(a.z); o[3] = f2bf(a.w);
    o[4] = f2bf(b.x); o[5] = f2bf(b.y); o[6] = f2bf(b.z); o[7] = f2bf(b.w);
    *(u16x8*)(Xb + i) = o;
}

// =====================================================================
// Pre-pass B: transpose-cast W [K][N] fp32 -> Wt [N][K] bf16
// 32x32 LDS tiles, grid (N/32, K/32)
// =====================================================================
__global__ __launch_bounds__(256) void tcast_kernel(
    const float* __restrict__ src, unsigned short* __restrict__ dst,
    int K, int N)
{
    __shared__ float ts[32][33];
    const int t = threadIdx.x;
    const int n0 = blockIdx.x * 32, k0 = blockIdx.y * 32;
    const int r = t >> 5, c = t & 31;
    #pragma unroll
    for (int p = 0; p < 4; ++p)
        ts[r + p * 8][c] = src[(size_t)(k0 + r + p * 8) * N + n0 + c];
    __syncthreads();
    #pragma unroll
    for (int p = 0; p < 4; ++p)
        dst[(size_t)(n0 + r + p * 8) * K + k0 + c] = f2bf(ts[c][r + p * 8]);
}

// =====================================================================
// Kernel 1: QKV projection via bf16 MFMA + fused RoPE + head-split.
// C = Xb[8192][1024] @ Wt^T  where Wt[3072][1024] = [Wq;Wkv]^T (bf16).
// 128x128 tile, 256 thr = 4 waves (2x2), each wave 64x64 = 4x4 MFMA
// tiles, BK=32, global_load_lds width-16 staging (m97 structure).
// Epilogue: RoPE via __shfl_xor(.,1) (pair = adjacent lanes), scatter
// bf16 to qb/kb/vb [b][h][n][64].
// MFMA layouts (m89-verified): A[m=lane&15][k=quad*8+j],
// B^T[n=lane&15][k=quad*8+j], C/D col=lane&15 row=quad*4+reg.
// =====================================================================
__global__ __launch_bounds__(256) void proj_qkv_mfma(
    const unsigned short* __restrict__ Xb, const unsigned short* __restrict__ Wt,
    unsigned short* __restrict__ qb, unsigned short* __restrict__ kb,
    unsigned short* __restrict__ vb)
{
    __shared__ __align__(16) unsigned short As[128 * 32];  // [m][k] contiguous
    __shared__ __align__(16) unsigned short Bs[128 * 32];  // [n][k] contiguous

    const int t     = threadIdx.x;
    const int w     = t >> 6, lane = t & 63;
    const int lane4 = lane & 15, quad = lane >> 4, quad8 = quad * 8;
    const int wm    = w >> 1, wn = w & 1;
    const int m0    = blockIdx.y * 128, n0 = blockIdx.x * 128;

    // staging maps: 16B unit u = p*256 + t; row = u/4, colElems = (u%4)*8
    const int srow = t >> 2, scol = (t & 3) * 8;
    const unsigned short* gA = Xb + (size_t)(m0 + srow) * DD + scol;
    const unsigned short* gB = Wt + (size_t)(n0 + srow) * DD + scol;
    unsigned short* lA = As + t * 8;
    unsigned short* lB = Bs + t * 8;

    f32x4 acc[4][4] = {};

    for (int k0 = 0; k0 < DD; k0 += 32) {
        __syncthreads();   // prior iter's frag reads done
        ASYNC16(gA + k0,            lA);
        ASYNC16(gA + 64 * DD + k0,  lA + 2048);
        ASYNC16(gB + k0,            lB);
        ASYNC16(gB + 64 * DD + k0,  lB + 2048);
        __syncthreads();   // vmcnt(0) drain + barrier

        bf16x8 a[4], b[4];
        #pragma unroll
        for (int i = 0; i < 4; ++i)
            a[i] = *(const bf16x8*)&As[(wm * 64 + i * 16 + lane4) * 32 + quad8];
        #pragma unroll
        for (int j = 0; j < 4; ++j)
            b[j] = *(const bf16x8*)&Bs[(wn * 64 + j * 16 + lane4) * 32 + quad8];
        #pragma unroll
        for (int i = 0; i < 4; ++i)
            #pragma unroll
            for (int j = 0; j < 4; ++j)
                acc[i][j] = __builtin_amdgcn_mfma_f32_16x16x32_bf16(
                    a[i], b[j], acc[i][j], 0, 0, 0);
    }

    // ---- epilogue: RoPE + scatter to [b][h][n][64] bf16 ----
    const int sec = n0 >> 10;                  // 0=q 1=k 2=v (uniform/block)
    unsigned short* dst = (sec == 0) ? qb : ((sec == 1) ? kb : vb);

    #pragma unroll
    for (int j = 0; j < 4; ++j) {
        const int csec = (n0 & 1023) + wn * 64 + j * 16;  // col within section
        const int h    = csec >> 6;
        const int dhb  = csec & 63;            // 0,16,32,48
        const int dh   = dhb + lane4;
        const bool rope = (sec < 2) && (dhb < 32);   // wave-uniform
        const float invf = exp2f(-(float)(dh >> 1) * LOG2_10K_D16);
        #pragma unroll
        for (int i = 0; i < 4; ++i) {
            #pragma unroll
            for (int r = 0; r < 4; ++r) {
                const int rg = m0 + wm * 64 + i * 16 + quad * 4 + r;
                const int b  = rg >> 11;
                const int n  = rg & 2047;
                float x = acc[i][j][r];
                if (rope) {
                    const float ang = (float)n * invf;
                    float s_, c_;
                    __sincosf(ang, &s_, &c_);
                    const float p = __shfl_xor(x, 1);
                    x = (lane4 & 1) ? fmaf(p, s_, x * c_)
                                    : fmaf(p, -s_, x * c_);
                }
                dst[(((size_t)b * HH + h) * NN + n) * DHD + dh] = f2bf(x);
            }
        }
    }
}

// =====================================================================
// Kernel 2: flash attention with bf16 MFMA (16x16x32) — as R2, but the
// epilogue writes bf16 ao so out_proj can async-stage it.
// =====================================================================
__global__ __launch_bounds__(256) void attn_kernel(
    const unsigned short* __restrict__ qb, const unsigned short* __restrict__ kb,
    const unsigned short* __restrict__ vb, unsigned short* __restrict__ aob)
{
    __shared__ __align__(16) unsigned short ks[64][72];    // [key][dh]
    __shared__ __align__(16) unsigned short vt[64][72];    // [dh][key]
    __shared__ __align__(16) unsigned short ps[4][16][72]; // per-wave P

    const int t     = threadIdx.x;
    const int w     = t >> 6;
    const int lane  = t & 63;
    const int lane4 = lane & 15;
    const int quad  = lane >> 4;
    const int quad8 = quad * 8;

    const int q0 = blockIdx.x * 64;
    const int bh = blockIdx.y;
    const size_t hb = (size_t)bh * NN * DHD;

    const unsigned short* qrow = qb + hb + (size_t)(q0 + w * 16 + lane4) * DHD;
    const bf16x8 qf0 = *(const bf16x8*)(qrow + quad8);
    const bf16x8 qf1 = *(const bf16x8*)(qrow + 32 + quad8);

    const int st_key = t >> 3;
    const int st_dh  = (t & 7) * 8;

    float m_r[4], l_r[4];
    f32x4 o[4];
    #pragma unroll
    for (int r = 0; r < 4; ++r) { m_r[r] = -1e30f; l_r[r] = 0.0f; }
    #pragma unroll
    for (int c = 0; c < 4; ++c) o[c] = (f32x4){0.f, 0.f, 0.f, 0.f};

    for (int kt = 0; kt < NN / 64; ++kt) {
        __syncthreads();

        #pragma unroll
        for (int p = 0; p < 2; ++p) {
            const int key = st_key + p * 32;
            const bf16x8 val = *(const bf16x8*)(kb + hb + (size_t)(kt * 64 + key) * DHD + st_dh);
            *(bf16x8*)&ks[key][st_dh] = val;
        }
        #pragma unroll
        for (int p = 0; p < 2; ++p) {
            const int dh0 = w * 16 + p * 8;
            const bf16x8 val = *(const bf16x8*)(vb + hb + (size_t)(kt * 64 + lane) * DHD + dh0);
            #pragma unroll
            for (int j = 0; j < 8; ++j) vt[dh0 + j][lane] = (unsigned short)val[j];
        }
        __syncthreads();

        f32x4 sc[4];
        #pragma unroll
        for (int c = 0; c < 4; ++c) {
            const bf16x8 b0 = *(const bf16x8*)&ks[c * 16 + lane4][quad8];
            const bf16x8 b1 = *(const bf16x8*)&ks[c * 16 + lane4][32 + quad8];
            f32x4 z = (f32x4){0.f, 0.f, 0.f, 0.f};
            z = __builtin_amdgcn_mfma_f32_16x16x32_bf16(qf0, b0, z, 0, 0, 0);
            z = __builtin_amdgcn_mfma_f32_16x16x32_bf16(qf1, b1, z, 0, 0, 0);
            sc[c] = z;
        }

        float tv[4][4];
        #pragma unroll
        for (int c = 0; c < 4; ++c)
            #pragma unroll
            for (int r = 0; r < 4; ++r)
                tv[c][r] = sc[c][r] * SCALE_LOG2E;

        float mrow[4];
        #pragma unroll
        for (int r = 0; r < 4; ++r)
            mrow[r] = fmaxf(fmaxf(tv[0][r], tv[1][r]), fmaxf(tv[2][r], tv[3][r]));
        #pragma unroll
        for (int off = 1; off <= 8; off <<= 1)
            #pragma unroll
            for (int r = 0; r < 4; ++r)
                mrow[r] = fmaxf(mrow[r], __shfl_xor(mrow[r], off));

        float alpha[4], rsum[4];
        #pragma unroll
        for (int r = 0; r < 4; ++r) {
            const float mnew = fmaxf(m_r[r], mrow[r]);
            alpha[r] = exp2f(m_r[r] - mnew);
            m_r[r] = mnew;
            rsum[r] = 0.0f;
        }
        #pragma unroll
        for (int c = 0; c < 4; ++c)
            #pragma unroll
            for (int r = 0; r < 4; ++r) {
                const float p = exp2f(tv[c][r] - m_r[r]);
                const unsigned short pb = f2bf(p);
                ps[w][quad * 4 + r][c * 16 + lane4] = pb;
                rsum[r] += bf2f(pb);
            }
        #pragma unroll
        for (int off = 1; off <= 8; off <<= 1)
            #pragma unroll
            for (int r = 0; r < 4; ++r)
                rsum[r] += __shfl_xor(rsum[r], off);
        #pragma unroll
        for (int r = 0; r < 4; ++r)
            l_r[r] = l_r[r] * alpha[r] + rsum[r];

        #pragma unroll
        for (int c = 0; c < 4; ++c)
            #pragma unroll
            for (int r = 0; r < 4; ++r)
                o[c][r] *= alpha[r];

        const bf16x8 pf0 = *(const bf16x8*)&ps[w][lane4][quad8];
        const bf16x8 pf1 = *(const bf16x8*)&ps[w][lane4][32 + quad8];

        #pragma unroll
        for (int c = 0; c < 4; ++c) {
            const bf16x8 v0 = *(const bf16x8*)&vt[c * 16 + lane4][quad8];
            const bf16x8 v1 = *(const bf16x8*)&vt[c * 16 + lane4][32 + quad8];
            o[c] = __builtin_amdgcn_mfma_f32_16x16x32_bf16(pf0, v0, o[c], 0, 0, 0);
            o[c] = __builtin_amdgcn_mfma_f32_16x16x32_bf16(pf1, v1, o[c], 0, 0, 0);
        }
    }

    const int b = bh >> 4, h = bh & 15;
    float linv[4];
    #pragma unroll
    for (int r = 0; r < 4; ++r) linv[r] = 1.0f / l_r[r];
    #pragma unroll
    for (int c = 0; c < 4; ++c)
        #pragma unroll
        for (int r = 0; r < 4; ++r) {
            const int n = q0 + w * 16 + quad * 4 + r;
            aob[((size_t)b * NN + n) * INNER + h * DHD + c * 16 + lane4] =
                f2bf(o[c][r] * linv[r]);
        }
}

// =====================================================================
// Kernel 3: output projection via bf16 MFMA.
// out = aob[8192][1024] @ WoT^T + bias  (WoT[1024 n][1024 k] bf16)
// =====================================================================
__global__ __launch_bounds__(256) void out_proj_mfma(
    const unsigned short* __restrict__ Ab, const unsigned short* __restrict__ Wt,
    const float* __restrict__ bias, float* __restrict__ C)
{
    __shared__ __align__(16) unsigned short As[128 * 32];
    __shared__ __align__(16) unsigned short Bs[128 * 32];

    const int t     = threadIdx.x;
    const int w     = t >> 6, lane = t & 63;
    const int lane4 = lane & 15, quad = lane >> 4, quad8 = quad * 8;
    const int wm    = w >> 1, wn = w & 1;
    const int m0    = blockIdx.y * 128, n0 = blockIdx.x * 128;

    const int srow = t >> 2, scol = (t & 3) * 8;
    const unsigned short* gA = Ab + (size_t)(m0 + srow) * INNER + scol;
    const unsigned short* gB = Wt + (size_t)(n0 + srow) * INNER + scol;
    unsigned short* lA = As + t * 8;
    unsigned short* lB = Bs + t * 8;

    f32x4 acc[4][4] = {};

    for (int k0 = 0; k0 < INNER; k0 += 32) {
        __syncthreads();
        ASYNC16(gA + k0,               lA);
        ASYNC16(gA + 64 * INNER + k0,  lA + 2048);
        ASYNC16(gB + k0,               lB);
        ASYNC16(gB + 64 * INNER + k0,  lB + 2048);
        __syncthreads();

        bf16x8 a[4], b[4];
        #pragma unroll
        for (int i = 0; i < 4; ++i)
            a[i] = *(const bf16x8*)&As[(wm * 64 + i * 16 + lane4) * 32 + quad8];
        #pragma unroll
        for (int j = 0; j < 4; ++j)
            b[j] = *(const bf16x8*)&Bs[(wn * 64 + j * 16 + lane4) * 32 + quad8];
        #pragma unroll
        for (int i = 0; i < 4; ++i)
            #pragma unroll
            for (int j = 0; j < 4; ++j)
                acc[i][j] = __builtin_amdgcn_mfma_f32_16x16x32_bf16(
                    a[i], b[j], acc[i][j], 0, 0, 0);
    }

    #pragma unroll
    for (int j = 0; j < 4; ++j) {
        const int col = n0 + wn * 64 + j * 16 + lane4;
        const float bv = bias[col];
        #pragma unroll
        for (int i = 0; i < 4; ++i)
            #pragma unroll
            for (int r = 0; r < 4; ++r) {
                const int rg = m0 + wm * 64 + i * 16 + quad * 4 + r;
                C[(size_t)rg * DD + col] = acc[i][j][r] + bv;
            }
    }
}

// =====================================================================
extern "C" void kernel_launch(void* const* d_in, const int* in_sizes, int n_in,
                              void* d_out, int out_size, void* d_ws, size_t ws_size,
                              hipStream_t stream)
{
    const float* X    = (const float*)d_in[0];   // (4,2048,1024)
    const float* Wq   = (const float*)d_in[1];   // (1024,1024)
    const float* Wkv  = (const float*)d_in[2];   // (1024,2048)
    const float* Wout = (const float*)d_in[3];   // (1024,1024)
    const float* bout = (const float*)d_in[4];   // (1024,)
    float* out = (float*)d_out;

    // ws (bf16 elems): qb|kb|vb|xb(=aob after proj)|WtAll|WoT  = 75.5 MB
    const size_t E = (size_t)BB * HH * NN * DHD;   // 8388608
    unsigned short* qb = (unsigned short*)d_ws;
    unsigned short* kb = qb + E;
    unsigned short* vb = kb + E;
    unsigned short* xb = vb + E;                 // X bf16; later reused as ao
    unsigned short* wt = xb + E;                 // [3072][1024] = WqT ; WkvT
    unsigned short* wo = wt + (size_t)3072 * 1024;  // [1024][1024]

    // pre-pass: casts + weight transposes
    cast_x_kernel<<<4096, 256, 0, stream>>>(X, xb);
    tcast_kernel<<<dim3(32, 32), 256, 0, stream>>>(Wq,   wt,                 1024, 1024);
    tcast_kernel<<<dim3(64, 32), 256, 0, stream>>>(Wkv,  wt + 1024 * 1024,   1024, 2048);
    tcast_kernel<<<dim3(32, 32), 256, 0, stream>>>(Wout, wo,                 1024, 1024);

    // Stage 1: QKV projection (MFMA) + RoPE + head split
    proj_qkv_mfma<<<dim3(3072 / 128, 8192 / 128), 256, 0, stream>>>(
        xb, wt, qb, kb, vb);

    // Stage 2: attention
    attn_kernel<<<dim3(NN / 64, BB * HH), 256, 0, stream>>>(qb, kb, vb, xb);

    // Stage 3: output projection (MFMA) + bias
    out_proj_mfma<<<dim3(1024 / 128, 8192 / 128), 256, 0, stream>>>(
        xb, wo, bout, out);
}